// Round 1
// baseline (295.603 us; speedup 1.0000x reference)
//
#include <hip/hip_runtime.h>

// PositionWiseSpatialAttention — fused flash-style kernel, MI355X gfx950.
//
// R6 = R5 with an occupancy restructure: 512-thread blocks (8 waves x 16 rows)
// instead of 256 (4 waves x 32 rows). Grid stays 768 (3 blocks/CU), so waves/CU
// goes 12 -> 24 (3 -> 6 per SIMD). R5 counters showed latency-bound behavior:
// MfmaUtil 28.5 (derived; real matrix-pipe busy ~9%), VALUBusy 35, HBM 15%,
// Occupancy 26.6 — nothing saturated. Per-wave work is halved and K/V staging
// is split across wave halves (waves 0-3 stage K, 4-7 stage V), so the serial
// split-chain between barriers shortens and 6 waves/SIMD cover each other's
// VALU/LDS phases with MFMA. Math, layouts, and LDS map identical to R5.

#define NB    8
#define NT    12
#define NNODE 1024
#define ND    64
#define XROW  768   /* NT*ND: stride between consecutive n for fixed (b,t) */

typedef __bf16 bf16x8 __attribute__((ext_vector_type(8)));
typedef float  floatx4 __attribute__((ext_vector_type(4)));

#define MFMA(a,b,c) __builtin_amdgcn_mfma_f32_16x16x32_bf16((a),(b),(c),0,0,0)

#define QSCALE 0.18033688011112042f   /* 0.125 * log2(e) */

// LDS layout (bytes); all row strides keep 16B alignment for b128 ops.
#define KSTRIDE 72   /* bf16 per K row: 144 B */
#define VSTRIDE 40   /* bf16 per V row:  80 B */
#define PSTRIDE 36   /* f32  per P row: 144 B */
#define AGSTRIDE 68  /* f32  per AG row (epilogue overlay) */
#define OFF_KHI 0
#define OFF_KLO 4608
#define OFF_VHI 9216
#define OFF_VLO 14336
#define OFF_P   19456
#define SMEM_BYTES (19456 + 128*PSTRIDE*4)   /* 37888 */

struct bfpair { __bf16 h, l; };

// error-compensated split: hi = RNE(f) via native fptrunc, lo = RNE(f - hi).
// |f - hi - lo| ~ 2^-17 |f|.
__device__ __forceinline__ bfpair split1(float f) {
    bfpair r;
    __bf16 hb = (__bf16)f;
    float hf = __builtin_bit_cast(float,
                   (unsigned)__builtin_bit_cast(unsigned short, hb) << 16);
    r.h = hb;
    r.l = (__bf16)(f - hf);
    return r;
}

__global__ void __launch_bounds__(512, 6)
spattn(const float* __restrict__ x, const float* __restrict__ adj,
       const float* __restrict__ theta, float* __restrict__ out)
{
    __shared__ __align__(16) char smem[SMEM_BYTES];
    __bf16* Khi = (__bf16*)(smem + OFF_KHI);
    __bf16* Klo = (__bf16*)(smem + OFF_KLO);
    __bf16* Vhi = (__bf16*)(smem + OFF_VHI);
    __bf16* Vlo = (__bf16*)(smem + OFF_VLO);
    float*  Pm  = (float*)(smem + OFF_P);

    const int tid  = threadIdx.x;
    const int wave = tid >> 6;          // 0..7, owns rows wave*16..wave*16+15
    const int lane = tid & 63;
    const int l16  = lane & 15;
    const int quad = lane >> 4;

    const int bx   = blockIdx.x;
    const int g    = bx >> 3;       // 0..95
    const int rblk = bx & 7;        // 0..7
    const int bb   = g / NT;
    const int tt   = g - bb * NT;
    const int row0 = rblk * 128;

    const float* xbase = x + (size_t)bb * (NNODE * XROW) + tt * ND;

    // ---- Q fragments (hi/lo), pre-scaled by 0.125*log2e, from global ----
    bf16x8 qhi[2], qlo[2];
    {
        const float* qsrc = xbase + (size_t)(row0 + wave*16 + l16) * XROW;
        #pragma unroll
        for (int ks = 0; ks < 2; ++ks) {
            floatx4 f0 = *(const floatx4*)(qsrc + ks*32 + quad*8);
            floatx4 f1 = *(const floatx4*)(qsrc + ks*32 + quad*8 + 4);
            #pragma unroll
            for (int i = 0; i < 4; ++i) {
                bfpair p0 = split1(f0[i]*QSCALE);
                qhi[ks][i]   = p0.h; qlo[ks][i]   = p0.l;
                bfpair p1 = split1(f1[i]*QSCALE);
                qhi[ks][4+i] = p1.h; qlo[ks][4+i] = p1.l;
            }
        }
    }

    const floatx4 vzero = {0.f, 0.f, 0.f, 0.f};
    floatx4 acc[4];
    #pragma unroll
    for (int dt = 0; dt < 4; ++dt) acc[dt] = vzero;
    float lpart[4] = {0.f, 0.f, 0.f, 0.f};

    // staging split across wave halves: waves 0-3 stage K, waves 4-7 stage V.
    // Maps within each 256-thread half are identical to R5's proven maps.
    const int half = tid >> 8;          // 0: K-stager, 1: V-stager
    const int htid = tid & 255;
    const int skey = htid >> 3;         // 0..31 (K: 1 key x 8 d, b128 writes)
    const int sd0  = (htid & 7) * 8;    // 0..56
    const int svd  = htid >> 2;         // 0..63 (V: 8 keys x 1 d)
    const int svk0 = (htid & 3) * 8;    // 0..24
    floatx4 kf0, kf1;
    float vf[8];

    if (half == 0) { // preload tile 0 (K half)
        const float* ksrc = xbase + (size_t)skey * XROW + sd0;
        kf0 = *(const floatx4*)ksrc;
        kf1 = *(const floatx4*)(ksrc + 4);
    } else {         // preload tile 0 (V half)
        const float* vsrc = xbase + (size_t)svk0 * XROW + svd;
        #pragma unroll
        for (int i = 0; i < 8; ++i) vf[i] = vsrc[i * XROW];
    }

    for (int ct = 0; ct < 32; ++ct) {
        const int key0 = ct * 32;
        __syncthreads();                       // prior tile's LDS reads done
        if (half == 0) { // store staged K (split hi/lo) to LDS
            bf16x8 h, l;
            #pragma unroll
            for (int i = 0; i < 4; ++i) {
                bfpair p0 = split1(kf0[i]); h[i]   = p0.h; l[i]   = p0.l;
                bfpair p1 = split1(kf1[i]); h[4+i] = p1.h; l[4+i] = p1.l;
            }
            *(bf16x8*)(Khi + skey*KSTRIDE + sd0) = h;
            *(bf16x8*)(Klo + skey*KSTRIDE + sd0) = l;
        } else {         // store staged V (split hi/lo) to LDS
            bf16x8 vh, vl;
            #pragma unroll
            for (int i = 0; i < 8; ++i) {
                bfpair p = split1(vf[i]); vh[i] = p.h; vl[i] = p.l;
            }
            *(bf16x8*)(Vhi + svd*VSTRIDE + svk0) = vh;
            *(bf16x8*)(Vlo + svd*VSTRIDE + svk0) = vl;
        }
        __syncthreads();                       // staging visible
        if (ct < 31) { // register prefetch of next tile, overlaps compute
            const int nk = key0 + 32;
            if (half == 0) {
                const float* ksrc = xbase + (size_t)(nk + skey) * XROW + sd0;
                kf0 = *(const floatx4*)ksrc;
                kf1 = *(const floatx4*)(ksrc + 4);
            } else {
                const float* vsrc = xbase + (size_t)(nk + svk0) * XROW + svd;
                #pragma unroll
                for (int i = 0; i < 8; ++i) vf[i] = vsrc[i * XROW];
            }
        }
        // adj prefetch (L2/L3-hot, issued before the MFMA burst)
        float av[2][4];
        #pragma unroll
        for (int nt = 0; nt < 2; ++nt)
            #pragma unroll
            for (int r = 0; r < 4; ++r)
                av[nt][r] = adj[(size_t)(row0 + wave*16 + quad*4 + r) * NNODE
                                + key0 + nt*16 + l16];

        // ---- S = Q K^T (3-term split bf16); S is pre-scaled for exp2 ----
        floatx4 S[2] = {vzero, vzero};
        #pragma unroll
        for (int ks = 0; ks < 2; ++ks) {
            #pragma unroll
            for (int nt = 0; nt < 2; ++nt) {
                bf16x8 bh = *(const bf16x8*)(Khi + (nt*16 + l16)*KSTRIDE + ks*32 + quad*8);
                bf16x8 bl = *(const bf16x8*)(Klo + (nt*16 + l16)*KSTRIDE + ks*32 + quad*8);
                S[nt] = MFMA(qhi[ks], bh, S[nt]);
                S[nt] = MFMA(qlo[ks], bh, S[nt]);
                S[nt] = MFMA(qhi[ks], bl, S[nt]);
            }
        }
        // ---- exp2, denominator, P = adj*exp -> LDS (own wave's rows) ----
        #pragma unroll
        for (int nt = 0; nt < 2; ++nt)
            #pragma unroll
            for (int r = 0; r < 4; ++r) {
                float w = __builtin_amdgcn_exp2f(S[nt][r]);
                lpart[r] += w;
                Pm[(wave*16 + quad*4 + r)*PSTRIDE + nt*16 + l16] = av[nt][r] * w;
            }
        // ---- agg += P . V (3-term split; P A-frags read back from LDS) ----
        bf16x8 pah, pal;
        {
            const float* pp = Pm + (wave*16 + l16)*PSTRIDE + quad*8;
            floatx4 p0 = *(const floatx4*)pp;
            floatx4 p1 = *(const floatx4*)(pp + 4);
            #pragma unroll
            for (int i = 0; i < 4; ++i) {
                bfpair q0 = split1(p0[i]); pah[i]   = q0.h; pal[i]   = q0.l;
                bfpair q1 = split1(p1[i]); pah[4+i] = q1.h; pal[4+i] = q1.l;
            }
        }
        #pragma unroll
        for (int dt = 0; dt < 4; ++dt) {
            bf16x8 vh = *(const bf16x8*)(Vhi + (dt*16 + l16)*VSTRIDE + quad*8);
            bf16x8 vl = *(const bf16x8*)(Vlo + (dt*16 + l16)*VSTRIDE + quad*8);
            acc[dt] = MFMA(pah, vh, acc[dt]);
            acc[dt] = MFMA(pal, vh, acc[dt]);
            acc[dt] = MFMA(pah, vl, acc[dt]);
        }
    }

    // ---- denominator reduce across the 16 lanes of each quad-group ----
    float linv[4];
    #pragma unroll
    for (int r = 0; r < 4; ++r) {
        float lv = lpart[r];
        lv += __shfl_xor(lv, 1);
        lv += __shfl_xor(lv, 2);
        lv += __shfl_xor(lv, 4);
        lv += __shfl_xor(lv, 8);
        linv[r] = 1.0f / lv;
    }

    // ---- epilogue: out = relu((agg/l) @ theta), split-bf16 MFMA ----
    __syncthreads();                           // everyone done with K/V/P
    float* AG = (float*)smem;                  // [128][AGSTRIDE] overlay
    #pragma unroll
    for (int dt = 0; dt < 4; ++dt)
        #pragma unroll
        for (int r = 0; r < 4; ++r)
            AG[(wave*16 + quad*4 + r)*AGSTRIDE + dt*16 + l16]
                = acc[dt][r] * linv[r];

    bf16x8 th[4][2], tl[4][2];                 // theta B-frags (hi/lo)
    #pragma unroll
    for (int ot = 0; ot < 4; ++ot)
        #pragma unroll
        for (int ks = 0; ks < 2; ++ks)
            #pragma unroll
            for (int j = 0; j < 8; ++j) {
                float tv = theta[(ks*32 + quad*8 + j)*ND + ot*16 + l16];
                bfpair p = split1(tv);
                th[ot][ks][j] = p.h; tl[ot][ks][j] = p.l;
            }

    floatx4 oacc[4];
    #pragma unroll
    for (int ot = 0; ot < 4; ++ot) oacc[ot] = vzero;
    __syncthreads();                           // AG visible to all waves
    #pragma unroll
    for (int ks = 0; ks < 2; ++ks) {
        bf16x8 ah, al;
        {
            const float* ap = AG + (wave*16 + l16)*AGSTRIDE + ks*32 + quad*8;
            floatx4 a0 = *(const floatx4*)ap;
            floatx4 a1 = *(const floatx4*)(ap + 4);
            #pragma unroll
            for (int i = 0; i < 4; ++i) {
                bfpair q0 = split1(a0[i]); ah[i]   = q0.h; al[i]   = q0.l;
                bfpair q1 = split1(a1[i]); ah[4+i] = q1.h; al[4+i] = q1.l;
            }
        }
        #pragma unroll
        for (int ot = 0; ot < 4; ++ot) {
            oacc[ot] = MFMA(ah, th[ot][ks], oacc[ot]);
            oacc[ot] = MFMA(al, th[ot][ks], oacc[ot]);
            oacc[ot] = MFMA(ah, tl[ot][ks], oacc[ot]);
        }
    }

    float* obase = out + (size_t)bb * (NNODE * XROW) + tt * ND;
    #pragma unroll
    for (int ot = 0; ot < 4; ++ot)
        #pragma unroll
        for (int r = 0; r < 4; ++r) {
            float v = oacc[ot][r];
            obase[(size_t)(row0 + wave*16 + quad*4 + r) * XROW + ot*16 + l16]
                = v > 0.f ? v : 0.f;
        }
}

extern "C" void kernel_launch(void* const* d_in, const int* in_sizes, int n_in,
                              void* d_out, int out_size, void* d_ws, size_t ws_size,
                              hipStream_t stream) {
    (void)in_sizes; (void)n_in; (void)d_ws; (void)ws_size; (void)out_size;
    const float* x     = (const float*)d_in[0];
    const float* adj   = (const float*)d_in[1];
    const float* theta = (const float*)d_in[2];
    float* out = (float*)d_out;
    spattn<<<dim3(768), dim3(512), 0, stream>>>(x, adj, theta, out);
}

// Round 2
// 213.685 us; speedup vs baseline: 1.3834x; 1.3834x over previous
//
#include <hip/hip_runtime.h>

// PositionWiseSpatialAttention — fused flash-style kernel, MI355X gfx950.
//
// R7: two-kernel scheme.
//  presplit: one-shot fp32 -> {hi,lo} bf16 split of x in row-major (Q/K) and
//            transposed (V) layouts + transposed-split theta, into workspace.
//            Removes ALL per-tile split VALU from the main kernel (R5 spent
//            ~40% of its VALUBusy on staging splits, re-done 8x per x row).
//  spattn2:  R5 structure but 64-row blocks (grid 1536, 256 thr) -> 5
//            blocks/CU resident (vs 3), staging = pure b128 load + ds_write.
//            Softmax scale folded as one f32 mul before exp2 (S*SC), so Q/K
//            both come unscaled from the shared split arrays.
// R6 post-mortem: launch_bounds(512,6) -> 40 VGPR -> epilogue spill storm
// (WRITE_SIZE 24.6->83 MB). This version keeps 256-thr blocks with a 102-VGPR
// budget (launch_bounds(256,5)); fallback to the verified R5 kernel if the
// workspace is too small.

#define NB    8
#define NT    12
#define NNODE 1024
#define ND    64
#define XROW  768   /* NT*ND: stride between consecutive n for fixed (b,t) */
#define NG    96    /* NB*NT */

typedef __bf16 bf16x8 __attribute__((ext_vector_type(8)));
typedef __bf16 bf16x4 __attribute__((ext_vector_type(4)));
typedef float  floatx4 __attribute__((ext_vector_type(4)));

#define MFMA(a,b,c) __builtin_amdgcn_mfma_f32_16x16x32_bf16((a),(b),(c),0,0,0)

#define QSCALE 0.18033688011112042f   /* 0.125 * log2(e) */

// LDS layout (bytes); all row strides keep 16B alignment for b128 ops.
#define KSTRIDE 72   /* bf16 per K row: 144 B */
#define VSTRIDE 40   /* bf16 per V row:  80 B */
#define PSTRIDE 36   /* f32  per P row: 144 B */
#define AGSTRIDE 68  /* f32  per AG row (epilogue overlay) */
#define OFF_KHI 0
#define OFF_KLO 4608
#define OFF_VHI 9216
#define OFF_VLO 14336
#define OFF_P   19456
#define SMEM2   (19456 + 64*PSTRIDE*4)    /* 28672: 64-row blocks  */
#define SMEM_FB (19456 + 128*PSTRIDE*4)   /* 37888: fallback (R5)  */

// workspace element offsets (__bf16 units)
#define WXHI  0          /* [96][1024][64] row-major hi  */
#define WXLO  6291456
#define WXTHI 12582912   /* [96][64][1024] transposed hi */
#define WXTLO 18874368
#define WTHI  25165824   /* [64 o][64 d] theta^T hi      */
#define WTLO  25169920
#define WS_BYTES 50348032ULL

struct bfpair { __bf16 h, l; };

// error-compensated split: hi = RNE(f) via native fptrunc, lo = RNE(f - hi).
// |f - hi - lo| ~ 2^-17 |f|.
__device__ __forceinline__ bfpair split1(float f) {
    bfpair r;
    __bf16 hb = (__bf16)f;
    float hf = __builtin_bit_cast(float,
                   (unsigned)__builtin_bit_cast(unsigned short, hb) << 16);
    r.h = hb;
    r.l = (__bf16)(f - hf);
    return r;
}

// ---------------------------------------------------------------------------
// presplit: grid 1536 (96 g x 16 n-blocks), 256 threads.
// Each block: 64x64 fp32 tile of one g-slice -> row-major split + LDS
// transpose -> transposed split. Blocks 0,1 also split theta^T.
// ---------------------------------------------------------------------------
__global__ void __launch_bounds__(256)
presplit(const float* __restrict__ x, const float* __restrict__ theta,
         __bf16* __restrict__ ws)
{
    __shared__ __align__(16) float T[64 * 68];
    const int tid  = threadIdx.x;
    const int bx   = blockIdx.x;
    const int g    = bx >> 4;
    const int nblk = bx & 15;
    const int bb   = g / NT;
    const int tt   = g - bb * NT;
    const int n0   = nblk * 64;

    __bf16* Xhi  = ws + WXHI  + (size_t)g * 65536;
    __bf16* Xlo  = ws + WXLO  + (size_t)g * 65536;
    __bf16* XThi = ws + WXTHI + (size_t)g * 65536;
    __bf16* XTlo = ws + WXTLO + (size_t)g * 65536;
    const float* xg = x + (size_t)bb * (NNODE * XROW) + (size_t)tt * ND;

    // coalesced load of 64x64 tile; row-major split written on the way in
    #pragma unroll
    for (int i = 0; i < 4; ++i) {
        int chunk = i * 256 + tid;        // 0..1023
        int n  = chunk >> 4;              // 0..63
        int c4 = (chunk & 15) * 4;        // 0..60
        floatx4 f = *(const floatx4*)(xg + (size_t)(n0 + n) * XROW + c4);
        *(floatx4*)(T + n * 68 + c4) = f;
        bf16x4 h, l;
        #pragma unroll
        for (int j = 0; j < 4; ++j) {
            bfpair p = split1(f[j]); h[j] = p.h; l[j] = p.l;
        }
        *(bf16x4*)(Xhi + (size_t)(n0 + n) * 64 + c4) = h;
        *(bf16x4*)(Xlo + (size_t)(n0 + n) * 64 + c4) = l;
    }
    __syncthreads();

    // transposed split: thread owns (d, 16 consecutive n)
    {
        const int d  = tid >> 2;          // 0..63
        const int nc = (tid & 3) * 16;    // 0..48
        bf16x8 h0, l0, h1, l1;
        #pragma unroll
        for (int j = 0; j < 8; ++j) {
            bfpair p = split1(T[(nc + j) * 68 + d]);     h0[j] = p.h; l0[j] = p.l;
            bfpair q = split1(T[(nc + 8 + j) * 68 + d]); h1[j] = q.h; l1[j] = q.l;
        }
        __bf16* dsth = XThi + (size_t)d * NNODE + n0 + nc;
        __bf16* dstl = XTlo + (size_t)d * NNODE + n0 + nc;
        *(bf16x8*)dsth = h0; *(bf16x8*)(dsth + 8) = h1;
        *(bf16x8*)dstl = l0; *(bf16x8*)(dstl + 8) = l1;
    }

    // theta^T split (tiny): Tt[o][d] = theta[d][o]
    if (bx < 2) {
        int c  = bx * 256 + tid;          // 0..511
        int o  = c >> 3;                  // 0..63
        int d0 = (c & 7) * 8;             // 0..56
        bf16x8 h, l;
        #pragma unroll
        for (int i = 0; i < 8; ++i) {
            bfpair p = split1(theta[(size_t)(d0 + i) * ND + o]);
            h[i] = p.h; l[i] = p.l;
        }
        *(bf16x8*)(ws + WTHI + (size_t)o * 64 + d0) = h;
        *(bf16x8*)(ws + WTLO + (size_t)o * 64 + d0) = l;
    }
}

// ---------------------------------------------------------------------------
// spattn2: grid 1536 (96 g x 16 row-blocks of 64), 256 threads, 4 waves x 16
// rows. Staging is pure copy from pre-split arrays; LDS maps as R5.
// ---------------------------------------------------------------------------
__global__ void __launch_bounds__(256, 5)
spattn2(const __bf16* __restrict__ ws, const float* __restrict__ adj,
        float* __restrict__ out)
{
    __shared__ __align__(16) char smem[SMEM2];
    __bf16* Khi = (__bf16*)(smem + OFF_KHI);
    __bf16* Klo = (__bf16*)(smem + OFF_KLO);
    __bf16* Vhi = (__bf16*)(smem + OFF_VHI);
    __bf16* Vlo = (__bf16*)(smem + OFF_VLO);
    float*  Pm  = (float*)(smem + OFF_P);

    const int tid  = threadIdx.x;
    const int wave = tid >> 6;          // 0..3, owns rows wave*16..+15
    const int lane = tid & 63;
    const int l16  = lane & 15;
    const int quad = lane >> 4;

    const int bx   = blockIdx.x;
    const int g    = bx >> 4;           // 0..95
    const int rblk = bx & 15;           // 0..15
    const int bb   = g / NT;
    const int tt   = g - bb * NT;
    const int row0 = rblk * 64;

    const __bf16* xh  = ws + WXHI  + (size_t)g * 65536;
    const __bf16* xl  = ws + WXLO  + (size_t)g * 65536;
    const __bf16* xth = ws + WXTHI + (size_t)g * 65536;
    const __bf16* xtl = ws + WXTLO + (size_t)g * 65536;

    // ---- Q fragments straight from split arrays (unscaled) ----
    bf16x8 qhi[2], qlo[2];
    {
        const __bf16* q0 = xh + (size_t)(row0 + wave*16 + l16) * 64;
        const __bf16* q1 = xl + (size_t)(row0 + wave*16 + l16) * 64;
        #pragma unroll
        for (int ks = 0; ks < 2; ++ks) {
            qhi[ks] = *(const bf16x8*)(q0 + ks*32 + quad*8);
            qlo[ks] = *(const bf16x8*)(q1 + ks*32 + quad*8);
        }
    }

    const floatx4 vzero = {0.f, 0.f, 0.f, 0.f};
    floatx4 acc[4];
    #pragma unroll
    for (int dt = 0; dt < 4; ++dt) acc[dt] = vzero;
    float lpart[4] = {0.f, 0.f, 0.f, 0.f};

    // staging maps (identical geometry to R5's proven maps)
    const int skey = tid >> 3;          // 0..31
    const int sd0  = (tid & 7) * 8;     // 0..56
    const int svd  = tid >> 2;          // 0..63
    const int svk0 = (tid & 3) * 8;     // 0..24

    bf16x8 kh, kl, pvh, pvl;            // register prefetch (tile 0)
    kh  = *(const bf16x8*)(xh  + (size_t)skey * 64 + sd0);
    kl  = *(const bf16x8*)(xl  + (size_t)skey * 64 + sd0);
    pvh = *(const bf16x8*)(xth + (size_t)svd * NNODE + svk0);
    pvl = *(const bf16x8*)(xtl + (size_t)svd * NNODE + svk0);

    for (int ct = 0; ct < 32; ++ct) {
        const int key0 = ct * 32;
        __syncthreads();                       // prior tile's LDS reads done
        *(bf16x8*)(Khi + skey*KSTRIDE + sd0)  = kh;
        *(bf16x8*)(Klo + skey*KSTRIDE + sd0)  = kl;
        *(bf16x8*)(Vhi + svd*VSTRIDE + svk0)  = pvh;
        *(bf16x8*)(Vlo + svd*VSTRIDE + svk0)  = pvl;
        __syncthreads();                       // staging visible
        if (ct < 31) { // register prefetch of next tile, overlaps compute
            const int nk = key0 + 32;
            kh  = *(const bf16x8*)(xh  + (size_t)(nk + skey) * 64 + sd0);
            kl  = *(const bf16x8*)(xl  + (size_t)(nk + skey) * 64 + sd0);
            pvh = *(const bf16x8*)(xth + (size_t)svd * NNODE + nk + svk0);
            pvl = *(const bf16x8*)(xtl + (size_t)svd * NNODE + nk + svk0);
        }
        // adj prefetch (L2/L3-hot, issued before the MFMA burst)
        float av[2][4];
        #pragma unroll
        for (int nt = 0; nt < 2; ++nt)
            #pragma unroll
            for (int r = 0; r < 4; ++r)
                av[nt][r] = adj[(size_t)(row0 + wave*16 + quad*4 + r) * NNODE
                                + key0 + nt*16 + l16];

        // ---- S = Q K^T (3-term split bf16), raw scale ----
        floatx4 S[2] = {vzero, vzero};
        #pragma unroll
        for (int ks = 0; ks < 2; ++ks) {
            #pragma unroll
            for (int nt = 0; nt < 2; ++nt) {
                bf16x8 bh = *(const bf16x8*)(Khi + (nt*16 + l16)*KSTRIDE + ks*32 + quad*8);
                bf16x8 bl = *(const bf16x8*)(Klo + (nt*16 + l16)*KSTRIDE + ks*32 + quad*8);
                S[nt] = MFMA(qhi[ks], bh, S[nt]);
                S[nt] = MFMA(qlo[ks], bh, S[nt]);
                S[nt] = MFMA(qhi[ks], bl, S[nt]);
            }
        }
        // ---- exp2 (scale folded here), denominator, P = adj*exp -> LDS ----
        #pragma unroll
        for (int nt = 0; nt < 2; ++nt)
            #pragma unroll
            for (int r = 0; r < 4; ++r) {
                float w = __builtin_amdgcn_exp2f(S[nt][r] * QSCALE);
                lpart[r] += w;
                Pm[(wave*16 + quad*4 + r)*PSTRIDE + nt*16 + l16] = av[nt][r] * w;
            }
        // ---- agg += P . V (3-term split; P A-frags read back from LDS) ----
        bf16x8 pah, pal;
        {
            const float* pp = Pm + (wave*16 + l16)*PSTRIDE + quad*8;
            floatx4 p0 = *(const floatx4*)pp;
            floatx4 p1 = *(const floatx4*)(pp + 4);
            #pragma unroll
            for (int i = 0; i < 4; ++i) {
                bfpair q0 = split1(p0[i]); pah[i]   = q0.h; pal[i]   = q0.l;
                bfpair q1 = split1(p1[i]); pah[4+i] = q1.h; pal[4+i] = q1.l;
            }
        }
        #pragma unroll
        for (int dt = 0; dt < 4; ++dt) {
            bf16x8 vvh = *(const bf16x8*)(Vhi + (dt*16 + l16)*VSTRIDE + quad*8);
            bf16x8 vvl = *(const bf16x8*)(Vlo + (dt*16 + l16)*VSTRIDE + quad*8);
            acc[dt] = MFMA(pah, vvh, acc[dt]);
            acc[dt] = MFMA(pal, vvh, acc[dt]);
            acc[dt] = MFMA(pah, vvl, acc[dt]);
        }
    }

    // ---- denominator reduce across the 16 lanes of each quad-group ----
    float linv[4];
    #pragma unroll
    for (int r = 0; r < 4; ++r) {
        float lv = lpart[r];
        lv += __shfl_xor(lv, 1);
        lv += __shfl_xor(lv, 2);
        lv += __shfl_xor(lv, 4);
        lv += __shfl_xor(lv, 8);
        linv[r] = 1.0f / lv;
    }

    // ---- epilogue: out = relu((agg/l) @ theta), split-bf16 MFMA ----
    __syncthreads();                           // everyone done with K/V/P
    float* AG = (float*)smem;                  // [64][AGSTRIDE] overlay
    #pragma unroll
    for (int dt = 0; dt < 4; ++dt)
        #pragma unroll
        for (int r = 0; r < 4; ++r)
            AG[(wave*16 + quad*4 + r)*AGSTRIDE + dt*16 + l16]
                = acc[dt][r] * linv[r];

    // theta B-frags from pre-split theta^T (b128 loads, zero conversion)
    const __bf16* Th = ws + WTHI;
    const __bf16* Tl = ws + WTLO;
    bf16x8 th[4][2], tlw[4][2];
    #pragma unroll
    for (int ot = 0; ot < 4; ++ot)
        #pragma unroll
        for (int ks = 0; ks < 2; ++ks) {
            th[ot][ks]  = *(const bf16x8*)(Th + (size_t)(ot*16 + l16)*64 + ks*32 + quad*8);
            tlw[ot][ks] = *(const bf16x8*)(Tl + (size_t)(ot*16 + l16)*64 + ks*32 + quad*8);
        }

    floatx4 oacc[4];
    #pragma unroll
    for (int ot = 0; ot < 4; ++ot) oacc[ot] = vzero;
    __syncthreads();                           // AG visible to all waves
    #pragma unroll
    for (int ks = 0; ks < 2; ++ks) {
        bf16x8 ah, al;
        {
            const float* ap = AG + (wave*16 + l16)*AGSTRIDE + ks*32 + quad*8;
            floatx4 a0 = *(const floatx4*)ap;
            floatx4 a1 = *(const floatx4*)(ap + 4);
            #pragma unroll
            for (int i = 0; i < 4; ++i) {
                bfpair q0 = split1(a0[i]); ah[i]   = q0.h; al[i]   = q0.l;
                bfpair q1 = split1(a1[i]); ah[4+i] = q1.h; al[4+i] = q1.l;
            }
        }
        #pragma unroll
        for (int ot = 0; ot < 4; ++ot) {
            oacc[ot] = MFMA(ah, th[ot][ks], oacc[ot]);
            oacc[ot] = MFMA(al, th[ot][ks], oacc[ot]);
            oacc[ot] = MFMA(ah, tlw[ot][ks], oacc[ot]);
        }
    }

    float* obase = out + (size_t)bb * (NNODE * XROW) + tt * ND;
    #pragma unroll
    for (int ot = 0; ot < 4; ++ot)
        #pragma unroll
        for (int r = 0; r < 4; ++r) {
            float v = oacc[ot][r];
            obase[(size_t)(row0 + wave*16 + quad*4 + r) * XROW + ot*16 + l16]
                = v > 0.f ? v : 0.f;
        }
}

// ---------------------------------------------------------------------------
// Fallback: verified R5 kernel (used only if workspace is too small).
// ---------------------------------------------------------------------------
__global__ void __launch_bounds__(256, 2)
spattn_fb(const float* __restrict__ x, const float* __restrict__ adj,
          const float* __restrict__ theta, float* __restrict__ out)
{
    __shared__ __align__(16) char smem[SMEM_FB];
    __bf16* Khi = (__bf16*)(smem + OFF_KHI);
    __bf16* Klo = (__bf16*)(smem + OFF_KLO);
    __bf16* Vhi = (__bf16*)(smem + OFF_VHI);
    __bf16* Vlo = (__bf16*)(smem + OFF_VLO);
    float*  Pm  = (float*)(smem + OFF_P);

    const int tid  = threadIdx.x;
    const int wave = tid >> 6;
    const int lane = tid & 63;
    const int l16  = lane & 15;
    const int quad = lane >> 4;

    const int bx   = blockIdx.x;
    const int g    = bx >> 3;
    const int rblk = bx & 7;
    const int bb   = g / NT;
    const int tt   = g - bb * NT;
    const int row0 = rblk * 128;

    const float* xbase = x + (size_t)bb * (NNODE * XROW) + tt * ND;

    bf16x8 qhi[2][2], qlo[2][2];
    #pragma unroll
    for (int mt = 0; mt < 2; ++mt) {
        const float* qsrc = xbase + (size_t)(row0 + wave*32 + mt*16 + l16) * XROW;
        #pragma unroll
        for (int ks = 0; ks < 2; ++ks) {
            floatx4 f0 = *(const floatx4*)(qsrc + ks*32 + quad*8);
            floatx4 f1 = *(const floatx4*)(qsrc + ks*32 + quad*8 + 4);
            #pragma unroll
            for (int i = 0; i < 4; ++i) {
                bfpair p0 = split1(f0[i]*QSCALE);
                qhi[mt][ks][i]   = p0.h; qlo[mt][ks][i]   = p0.l;
                bfpair p1 = split1(f1[i]*QSCALE);
                qhi[mt][ks][4+i] = p1.h; qlo[mt][ks][4+i] = p1.l;
            }
        }
    }

    const floatx4 vzero = {0.f, 0.f, 0.f, 0.f};
    floatx4 acc[2][4];
    #pragma unroll
    for (int mt = 0; mt < 2; ++mt)
        #pragma unroll
        for (int dt = 0; dt < 4; ++dt)
            acc[mt][dt] = vzero;
    float lpart[2][4] = {{0.f,0.f,0.f,0.f},{0.f,0.f,0.f,0.f}};

    const int skey = tid >> 3;
    const int sd0  = (tid & 7) * 8;
    const int svd  = tid >> 2;
    const int svk0 = (tid & 3) * 8;
    floatx4 kf0, kf1;
    float vf[8];

    {
        const float* ksrc = xbase + (size_t)skey * XROW + sd0;
        kf0 = *(const floatx4*)ksrc;
        kf1 = *(const floatx4*)(ksrc + 4);
        const float* vsrc = xbase + (size_t)svk0 * XROW + svd;
        #pragma unroll
        for (int i = 0; i < 8; ++i) vf[i] = vsrc[i * XROW];
    }

    for (int ct = 0; ct < 32; ++ct) {
        const int key0 = ct * 32;
        __syncthreads();
        {
            bf16x8 h, l;
            #pragma unroll
            for (int i = 0; i < 4; ++i) {
                bfpair p0 = split1(kf0[i]); h[i]   = p0.h; l[i]   = p0.l;
                bfpair p1 = split1(kf1[i]); h[4+i] = p1.h; l[4+i] = p1.l;
            }
            *(bf16x8*)(Khi + skey*KSTRIDE + sd0) = h;
            *(bf16x8*)(Klo + skey*KSTRIDE + sd0) = l;
            bf16x8 vh, vl;
            #pragma unroll
            for (int i = 0; i < 8; ++i) {
                bfpair p = split1(vf[i]); vh[i] = p.h; vl[i] = p.l;
            }
            *(bf16x8*)(Vhi + svd*VSTRIDE + svk0) = vh;
            *(bf16x8*)(Vlo + svd*VSTRIDE + svk0) = vl;
        }
        __syncthreads();
        if (ct < 31) {
            const int nk = key0 + 32;
            const float* ksrc = xbase + (size_t)(nk + skey) * XROW + sd0;
            kf0 = *(const floatx4*)ksrc;
            kf1 = *(const floatx4*)(ksrc + 4);
            const float* vsrc = xbase + (size_t)(nk + svk0) * XROW + svd;
            #pragma unroll
            for (int i = 0; i < 8; ++i) vf[i] = vsrc[i * XROW];
        }
        float av[2][2][4];
        #pragma unroll
        for (int mt = 0; mt < 2; ++mt)
            #pragma unroll
            for (int nt = 0; nt < 2; ++nt)
                #pragma unroll
                for (int r = 0; r < 4; ++r)
                    av[mt][nt][r] = adj[(size_t)(row0 + wave*32 + mt*16 + quad*4 + r) * NNODE
                                        + key0 + nt*16 + l16];

        floatx4 S[2][2] = {{vzero, vzero}, {vzero, vzero}};
        #pragma unroll
        for (int ks = 0; ks < 2; ++ks) {
            #pragma unroll
            for (int nt = 0; nt < 2; ++nt) {
                bf16x8 bh = *(const bf16x8*)(Khi + (nt*16 + l16)*KSTRIDE + ks*32 + quad*8);
                bf16x8 bl = *(const bf16x8*)(Klo + (nt*16 + l16)*KSTRIDE + ks*32 + quad*8);
                #pragma unroll
                for (int mt = 0; mt < 2; ++mt) {
                    S[mt][nt] = MFMA(qhi[mt][ks], bh, S[mt][nt]);
                    S[mt][nt] = MFMA(qlo[mt][ks], bh, S[mt][nt]);
                    S[mt][nt] = MFMA(qhi[mt][ks], bl, S[mt][nt]);
                }
            }
        }
        #pragma unroll
        for (int mt = 0; mt < 2; ++mt)
            #pragma unroll
            for (int nt = 0; nt < 2; ++nt)
                #pragma unroll
                for (int r = 0; r < 4; ++r) {
                    float w = __builtin_amdgcn_exp2f(S[mt][nt][r]);
                    lpart[mt][r] += w;
                    Pm[(wave*32 + mt*16 + quad*4 + r)*PSTRIDE + nt*16 + l16] = av[mt][nt][r] * w;
                }
        bf16x8 pah[2], pal[2];
        #pragma unroll
        for (int mt = 0; mt < 2; ++mt) {
            const float* pp = Pm + (wave*32 + mt*16 + l16)*PSTRIDE + quad*8;
            floatx4 p0 = *(const floatx4*)pp;
            floatx4 p1 = *(const floatx4*)(pp + 4);
            #pragma unroll
            for (int i = 0; i < 4; ++i) {
                bfpair q0 = split1(p0[i]); pah[mt][i]   = q0.h; pal[mt][i]   = q0.l;
                bfpair q1 = split1(p1[i]); pah[mt][4+i] = q1.h; pal[mt][4+i] = q1.l;
            }
        }
        #pragma unroll
        for (int dt = 0; dt < 4; ++dt) {
            bf16x8 vh = *(const bf16x8*)(Vhi + (dt*16 + l16)*VSTRIDE + quad*8);
            bf16x8 vl = *(const bf16x8*)(Vlo + (dt*16 + l16)*VSTRIDE + quad*8);
            #pragma unroll
            for (int mt = 0; mt < 2; ++mt) {
                acc[mt][dt] = MFMA(pah[mt], vh, acc[mt][dt]);
                acc[mt][dt] = MFMA(pal[mt], vh, acc[mt][dt]);
                acc[mt][dt] = MFMA(pah[mt], vl, acc[mt][dt]);
            }
        }
    }

    float linv[2][4];
    #pragma unroll
    for (int mt = 0; mt < 2; ++mt)
        #pragma unroll
        for (int r = 0; r < 4; ++r) {
            float lv = lpart[mt][r];
            lv += __shfl_xor(lv, 1);
            lv += __shfl_xor(lv, 2);
            lv += __shfl_xor(lv, 4);
            lv += __shfl_xor(lv, 8);
            linv[mt][r] = 1.0f / lv;
        }

    __syncthreads();
    float* AG = (float*)smem;
    #pragma unroll
    for (int mt = 0; mt < 2; ++mt)
        #pragma unroll
        for (int dt = 0; dt < 4; ++dt)
            #pragma unroll
            for (int r = 0; r < 4; ++r)
                AG[(wave*32 + mt*16 + quad*4 + r)*AGSTRIDE + dt*16 + l16]
                    = acc[mt][dt][r] * linv[mt][r];

    bf16x8 th[4][2], tl[4][2];
    #pragma unroll
    for (int ot = 0; ot < 4; ++ot)
        #pragma unroll
        for (int ks = 0; ks < 2; ++ks)
            #pragma unroll
            for (int j = 0; j < 8; ++j) {
                float tv = theta[(ks*32 + quad*8 + j)*ND + ot*16 + l16];
                bfpair p = split1(tv);
                th[ot][ks][j] = p.h; tl[ot][ks][j] = p.l;
            }

    floatx4 oacc[2][4];
    #pragma unroll
    for (int mt = 0; mt < 2; ++mt)
        #pragma unroll
        for (int ot = 0; ot < 4; ++ot)
            oacc[mt][ot] = vzero;
    __syncthreads();
    #pragma unroll
    for (int ks = 0; ks < 2; ++ks) {
        bf16x8 ah[2], al[2];
        #pragma unroll
        for (int mt = 0; mt < 2; ++mt) {
            const float* ap = AG + (wave*32 + mt*16 + l16)*AGSTRIDE + ks*32 + quad*8;
            floatx4 a0 = *(const floatx4*)ap;
            floatx4 a1 = *(const floatx4*)(ap + 4);
            #pragma unroll
            for (int i = 0; i < 4; ++i) {
                bfpair q0 = split1(a0[i]); ah[mt][i]   = q0.h; al[mt][i]   = q0.l;
                bfpair q1 = split1(a1[i]); ah[mt][4+i] = q1.h; al[mt][4+i] = q1.l;
            }
        }
        #pragma unroll
        for (int ot = 0; ot < 4; ++ot)
            #pragma unroll
            for (int mt = 0; mt < 2; ++mt) {
                oacc[mt][ot] = MFMA(ah[mt], th[ot][ks], oacc[mt][ot]);
                oacc[mt][ot] = MFMA(al[mt], th[ot][ks], oacc[mt][ot]);
                oacc[mt][ot] = MFMA(ah[mt], tl[ot][ks], oacc[mt][ot]);
            }
    }

    float* obase = out + (size_t)bb * (NNODE * XROW) + tt * ND;
    #pragma unroll
    for (int mt = 0; mt < 2; ++mt)
        #pragma unroll
        for (int ot = 0; ot < 4; ++ot)
            #pragma unroll
            for (int r = 0; r < 4; ++r) {
                float v = oacc[mt][ot][r];
                obase[(size_t)(row0 + wave*32 + mt*16 + quad*4 + r) * XROW + ot*16 + l16]
                    = v > 0.f ? v : 0.f;
            }
}

extern "C" void kernel_launch(void* const* d_in, const int* in_sizes, int n_in,
                              void* d_out, int out_size, void* d_ws, size_t ws_size,
                              hipStream_t stream) {
    (void)in_sizes; (void)n_in; (void)out_size;
    const float* x     = (const float*)d_in[0];
    const float* adj   = (const float*)d_in[1];
    const float* theta = (const float*)d_in[2];
    float* out = (float*)d_out;
    if (d_ws != nullptr && ws_size >= WS_BYTES) {
        __bf16* ws = (__bf16*)d_ws;
        presplit<<<dim3(1536), dim3(256), 0, stream>>>(x, theta, ws);
        spattn2<<<dim3(1536), dim3(256), 0, stream>>>(ws, adj, out);
    } else {
        spattn_fb<<<dim3(768), dim3(256), 0, stream>>>(x, adj, theta, out);
    }
}